// Round 1
// baseline (1401.937 us; speedup 1.0000x reference)
//
#include <hip/hip_runtime.h>
#include <hip/hip_bf16.h>

// EfficientInteractionBilinear on MI355X (gfx950)
//
// out[e,o] = sum_{i,c} A[e,i,c] * W[c,i,o],  A[e] = (rbf[e] @ sph[e]) @ m2[e]
// Fused per-16-edge-tile kernel:
//   prologue: B[e](64x16) = rbf[e](64x16) @ sph[e](16x16)      [MFMA, K=16 pad 32]
//   per c-chunk(16): m2t scatter -> A_chunk = B @ m2t          [MFMA, K=16 pad 32]
//                    out_tile += X_c(16x64) @ W[c](64x128)     [MFMA, K=64]
// Weight pre-transposed to bf16 [c][o][i] in d_ws (2 MB) so B-fragments are
// contiguous 16B loads (L2-resident re-reads).

typedef __attribute__((ext_vector_type(8))) short short8;
typedef __attribute__((ext_vector_type(4))) short short4v;
typedef __attribute__((ext_vector_type(4))) float f32x4;

#define S_DIM   16
#define KMAXX   16
#define EMB     128
#define INTERM  64
#define NOUT    128

#define TE      16                  // edges per block (50000 % 16 == 0)
#define CB      16                  // EMB chunk width
#define NCHUNK  (EMB / CB)          // 8

#define BL_I    16                  // Blds k-row stride (elems)
#define AC_I    72                  // Ach i-row stride (padded from 64, 16B-mult)
#define AC_C    (TE * AC_I + 8)     // Ach per-c' stride = 1160 (16B-mult)

__device__ __forceinline__ short f2bf(float f) {
    union { float f; unsigned u; } v; v.f = f;
    unsigned r = v.u + 0x7fffu + ((v.u >> 16) & 1u);   // RNE
    return (short)(r >> 16);
}

// ---------------------------------------------------------------------------
// weight (c,i,o) fp32 -> wbf[c][o][i] bf16  (2 MB into d_ws)
// ---------------------------------------------------------------------------
__global__ __launch_bounds__(256) void wtrans_kernel(const float* __restrict__ w,
                                                     short* __restrict__ wbf) {
    __shared__ float ws[INTERM * (NOUT + 1)];
    const int c = blockIdx.x;
    const float* wc = w + (long)c * INTERM * NOUT;
    #pragma unroll
    for (int r = 0; r < (INTERM * NOUT) / 256; ++r) {
        int idx = threadIdx.x + r * 256;        // idx = i*128 + o (coalesced read)
        int i = idx >> 7, o = idx & 127;
        ws[i * (NOUT + 1) + o] = wc[idx];
    }
    __syncthreads();
    short* wo = wbf + (long)c * NOUT * INTERM;
    #pragma unroll
    for (int r = 0; r < (INTERM * NOUT) / 256; ++r) {
        int idx = threadIdx.x + r * 256;        // idx = o*64 + i (coalesced write)
        int o = idx >> 6, i = idx & 63;
        wo[idx] = f2bf(ws[i * (NOUT + 1) + o]);
    }
}

// ---------------------------------------------------------------------------
// fused main kernel: one block = 16 edges, 256 threads (4 waves)
// ---------------------------------------------------------------------------
__global__ __launch_bounds__(256) void fused_kernel(
    const float* __restrict__ rbf, const float* __restrict__ sph,
    const float* __restrict__ m,   const int* __restrict__ id_reduce,
    const int* __restrict__ id_rag, const short* __restrict__ wbf,
    float* __restrict__ out)
{
    __shared__ __align__(16) short Blds[TE * INTERM * BL_I];   // 32 KB  B[e][i][k]
    __shared__ __align__(16) short m2t[TE * CB * KMAXX];       //  8 KB  [e][c'][k]
    __shared__ __align__(16) short Ach[CB * AC_C];             // ~36 KB [c'][e][i]

    const int tid  = threadIdx.x;
    const int wave = tid >> 6;
    const int lane = tid & 63;
    const int l15  = lane & 15;
    const int q    = lane >> 4;
    const int e0   = blockIdx.x * TE;

    // ---- prologue: B[e] = rbf[e] @ sph[e], bf16 into Blds -------------------
    // wave handles edges wave*4 .. wave*4+3
    #pragma unroll
    for (int ee = 0; ee < 4; ++ee) {
        const int e = wave * 4 + ee;
        const long ge = (long)(e0 + e);
        short8 bfrag = {0,0,0,0,0,0,0,0};          // sph frag: B[k=s][n=kmax-col]
        if (q < 2) {
            const float* sp = sph + ge * (S_DIM * KMAXX) + (q * 8) * KMAXX + l15;
            #pragma unroll
            for (int j = 0; j < 8; ++j) bfrag[j] = f2bf(sp[j * KMAXX]);
        }
        #pragma unroll
        for (int it = 0; it < 4; ++it) {
            short8 afrag = {0,0,0,0,0,0,0,0};      // rbf frag: A[m=i][k=s]
            if (q < 2) {
                const float* rp = rbf + ge * (INTERM * S_DIM) + (it * 16 + l15) * S_DIM + q * 8;
                #pragma unroll
                for (int j = 0; j < 8; ++j) afrag[j] = f2bf(rp[j]);
            }
            f32x4 d = {0.f, 0.f, 0.f, 0.f};
            d = __builtin_amdgcn_mfma_f32_16x16x32_bf16(afrag, bfrag, d, 0, 0, 0);
            // D: row i = it*16 + q*4 + r, col k = l15
            #pragma unroll
            for (int r = 0; r < 4; ++r)
                Blds[e * (INTERM * BL_I) + (it * 16 + q * 4 + r) * BL_I + l15] = f2bf(d[r]);
        }
    }

    f32x4 acc[2];
    acc[0] = (f32x4){0.f, 0.f, 0.f, 0.f};
    acc[1] = (f32x4){0.f, 0.f, 0.f, 0.f};

    for (int ch = 0; ch < NCHUNK; ++ch) {
        const int c0 = ch * CB;

        // ---- zero m2t --------------------------------------------------------
        {
            int* mz = (int*)m2t;
            #pragma unroll
            for (int r = 0; r < (TE * CB * KMAXX) / 2 / 256; ++r)
                mz[tid + r * 256] = 0;
        }
        __syncthreads();   // zero visible before scatter; also fences prologue's Blds

        // ---- scatter m chunk into m2t[e][c'][slot] ---------------------------
        #pragma unroll
        for (int r = 0; r < (TE * 8 * CB) / 256; ++r) {
            int idx  = tid + r * 256;
            int trip = idx >> 4;                 // 0..127 (8 triplets/edge)
            int cc   = idx & 15;
            long t   = (long)e0 * 8 + trip;
            int el   = id_reduce[t] - e0;
            int slot = id_rag[t];
            float mv = m[t * EMB + c0 + cc];
            if (el >= 0 && el < TE && slot >= 0 && slot < KMAXX)
                m2t[(el * CB + cc) * KMAXX + slot] = f2bf(mv);
        }
        __syncthreads();   // m2t ready; all waves done with prev-chunk stage C

        // ---- stage B': A_chunk[c'][e][i] = B[e](64x16) @ m2t[e](16x16) -------
        #pragma unroll
        for (int ee = 0; ee < 4; ++ee) {
            const int e = wave * 4 + ee;
            short8 bfrag = {0,0,0,0,0,0,0,0};    // m2t frag: B[k=slot][n=c']
            if (q < 2)
                bfrag = *(const short8*)&m2t[(e * CB + l15) * KMAXX + q * 8];
            #pragma unroll
            for (int it = 0; it < 4; ++it) {
                short8 afrag = {0,0,0,0,0,0,0,0}; // Blds frag: A[m=i][k=slot]
                if (q < 2)
                    afrag = *(const short8*)&Blds[e * (INTERM * BL_I) + (it * 16 + l15) * BL_I + q * 8];
                f32x4 d = {0.f, 0.f, 0.f, 0.f};
                d = __builtin_amdgcn_mfma_f32_16x16x32_bf16(afrag, bfrag, d, 0, 0, 0);
                // D: row i = it*16 + q*4 + r, col c' = l15 -> Ach[c'][e][i], 4 consec i
                short4v p;
                #pragma unroll
                for (int r = 0; r < 4; ++r) p[r] = f2bf(d[r]);
                *(short4v*)&Ach[l15 * AC_C + e * AC_I + it * 16 + q * 4] = p;
            }
        }
        __syncthreads();   // Ach ready

        // ---- stage C: out_tile += X_c(16x64) @ W[c](64x128), per c' ----------
        #pragma unroll 4
        for (int cc = 0; cc < CB; ++cc) {
            const int c = c0 + cc;
            // A frags: A[m=e][k=i], e = l15, i = ks*32 + q*8 + j
            short8 a0 = *(const short8*)&Ach[cc * AC_C + l15 * AC_I + 0  + q * 8];
            short8 a1 = *(const short8*)&Ach[cc * AC_C + l15 * AC_I + 32 + q * 8];
            #pragma unroll
            for (int nt = 0; nt < 2; ++nt) {
                const int n = (wave * 2 + nt) * 16 + l15;
                const short* wp = wbf + ((long)c * NOUT + n) * INTERM + q * 8;
                short8 b0 = *(const short8*)(wp);
                short8 b1 = *(const short8*)(wp + 32);
                acc[nt] = __builtin_amdgcn_mfma_f32_16x16x32_bf16(a0, b0, acc[nt], 0, 0, 0);
                acc[nt] = __builtin_amdgcn_mfma_f32_16x16x32_bf16(a1, b1, acc[nt], 0, 0, 0);
            }
        }
        __syncthreads();   // done with Ach/m2t before next chunk overwrites
    }

    // ---- epilogue: out[e0 + q*4 + r][ (wave*2+nt)*16 + l15 ] -----------------
    #pragma unroll
    for (int nt = 0; nt < 2; ++nt) {
        const int o = (wave * 2 + nt) * 16 + l15;
        #pragma unroll
        for (int r = 0; r < 4; ++r)
            out[(long)(e0 + q * 4 + r) * NOUT + o] = acc[nt][r];
    }
}

// ---------------------------------------------------------------------------
extern "C" void kernel_launch(void* const* d_in, const int* in_sizes, int n_in,
                              void* d_out, int out_size, void* d_ws, size_t ws_size,
                              hipStream_t stream) {
    const float* rbf = (const float*)d_in[0];
    const float* sph = (const float*)d_in[1];
    const float* m   = (const float*)d_in[2];
    const float* w   = (const float*)d_in[3];
    const int* idr   = (const int*)d_in[4];
    const int* idg   = (const int*)d_in[5];
    float* out       = (float*)d_out;
    short* wbf       = (short*)d_ws;           // 128*128*64 bf16 = 2 MB

    const int E = in_sizes[1] / (S_DIM * KMAXX);   // 50000

    hipLaunchKernelGGL(wtrans_kernel, dim3(EMB), dim3(256), 0, stream, w, wbf);
    hipLaunchKernelGGL(fused_kernel, dim3(E / TE), dim3(256), 0, stream,
                       rbf, sph, m, idr, idg, wbf, out);
}

// Round 2
// 1143.650 us; speedup vs baseline: 1.2258x; 1.2258x over previous
//
#include <hip/hip_runtime.h>
#include <hip/hip_bf16.h>

// EfficientInteractionBilinear on MI355X (gfx950) — v2
// out[e,o] = sum_{i,c} A[e,i,c] W[c,i,o],
//   sum_k[e,s,c'] = sph[e] @ m2[e]   (MFMA 16x16x32, K=16 of 32)
//   A[e,i,c']     = rbf[e] @ sum_k   (MFMA 32x32x16, K=16 exact; rbf frags in regs)
//   out          += A_chunk @ W[c]   (MFMA 16x16x32, K=64 full)
// 3 barriers/chunk, LDS 52.5 KB -> 3 blocks/CU, m prefetched 1 chunk ahead.

typedef __attribute__((ext_vector_type(8)))  short short8;
typedef __attribute__((ext_vector_type(4)))  short short4v;
typedef __attribute__((ext_vector_type(4)))  float f32x4;
typedef __attribute__((ext_vector_type(16))) float f32x16;
typedef __attribute__((ext_vector_type(4)))  float float4v;

#define S_DIM   16
#define KMAXX   16
#define EMB     128
#define INTERM  64
#define NOUT    128

#define TE      16
#define CB      16
#define NCH     8
#define EPAD    264                 // m2t per-edge stride (shorts), +8 pad
#define AC_I    72                  // Ach i-stride (64 padded, 16B mult)
#define AC_C    (TE * AC_I + 8)     // 1160

__device__ __forceinline__ short f2bf(float f) {
    union { float f; unsigned u; } v; v.f = f;
    unsigned r = v.u + 0x7fffu + ((v.u >> 16) & 1u);   // RNE
    return (short)(r >> 16);
}
__device__ __forceinline__ unsigned pk2(float a, float b) {
    float2 f; f.x = a; f.y = b;
    union { __hip_bfloat162 h; unsigned u; } c;
    c.h = __float22bfloat162_rn(f);
    return c.u;
}
__device__ __forceinline__ short4v pk4(float a, float b, float c, float d) {
    union { unsigned u[2]; short4v s; } r;
    r.u[0] = pk2(a, b); r.u[1] = pk2(c, d);
    return r.s;
}
__device__ __forceinline__ short8 pk8(float4v lo, float4v hi) {
    union { unsigned u[4]; short8 s; } r;
    r.u[0] = pk2(lo[0], lo[1]); r.u[1] = pk2(lo[2], lo[3]);
    r.u[2] = pk2(hi[0], hi[1]); r.u[3] = pk2(hi[2], hi[3]);
    return r.s;
}

// ---------------------------------------------------------------------------
// weight (c,i,o) fp32 -> wbf[c][o][i] bf16  (2 MB into d_ws)
// ---------------------------------------------------------------------------
__global__ __launch_bounds__(256) void wtrans_kernel(const float* __restrict__ w,
                                                     short* __restrict__ wbf) {
    __shared__ float ws[INTERM * (NOUT + 1)];
    const int c = blockIdx.x;
    const float* wc = w + (long)c * INTERM * NOUT;
    #pragma unroll
    for (int r = 0; r < (INTERM * NOUT) / 256; ++r) {
        int idx = threadIdx.x + r * 256;
        int i = idx >> 7, o = idx & 127;
        ws[i * (NOUT + 1) + o] = wc[idx];
    }
    __syncthreads();
    short* wo = wbf + (long)c * NOUT * INTERM;
    #pragma unroll
    for (int r = 0; r < (INTERM * NOUT) / 256; ++r) {
        int idx = threadIdx.x + r * 256;
        int o = idx >> 6, i = idx & 63;
        wo[idx] = f2bf(ws[i * (NOUT + 1) + o]);
    }
}

// ---------------------------------------------------------------------------
// fused kernel: one block = 16 edges, 256 threads (4 waves)
// ---------------------------------------------------------------------------
__global__ __launch_bounds__(256, 3) void fused_kernel(
    const float* __restrict__ rbf, const float* __restrict__ sph,
    const float* __restrict__ m,   const int* __restrict__ id_reduce,
    const int* __restrict__ id_rag, const short* __restrict__ wbf,
    float* __restrict__ out)
{
    __shared__ __align__(16) short m2t[TE * EPAD];    //  8448 B  [e][c'][k]
    __shared__ __align__(16) short swk[TE * 256];     //  8192 B  per-edge [c'][s]
    __shared__ __align__(16) short Ach[CB * AC_C];    // 37120 B  [c'][e][i]

    const int tid  = threadIdx.x;
    const int w    = tid >> 6;
    const int lane = tid & 63;
    const int l15  = lane & 15;
    const int q    = lane >> 4;
    const int c31  = lane & 31;
    const int hh   = lane >> 5;
    const int e0   = blockIdx.x * TE;

    // zero m2t once (slots >=8 must be 0; write set identical every chunk)
    for (int i = tid; i < (TE * EPAD) / 2; i += 256) ((int*)m2t)[i] = 0;

    // ---- ragged ids: thread <-> (triplet, channel-half) ---------------------
    const int trip = tid >> 1;
    const int hf   = tid & 1;
    const long t   = (long)e0 * 8 + trip;
    const int el   = id_reduce[t] - e0;
    const int slot = id_rag[t];
    const bool valid = (el >= 0) && (el < TE) && (slot >= 0) && (slot < KMAXX);
    const int sbase  = el * EPAD + hf * 8 * KMAXX + slot;
    const float* mrow = m + t * EMB + hf * 8;

    // ---- register fragments: sph (MFMA1-A), rbf (MFMA2-A) -------------------
    short8 sph_fr[4];
    short8 rbf_fr[4][2];
    #pragma unroll
    for (int ee = 0; ee < 4; ++ee) {
        const long ge = e0 + w * 4 + ee;
        if (q < 2) {
            const float* sp = sph + ge * (S_DIM * KMAXX) + l15 * KMAXX + q * 8;
            float4v s0 = *(const float4v*)sp;
            float4v s1 = *(const float4v*)(sp + 4);
            sph_fr[ee] = pk8(s0, s1);
        } else {
            sph_fr[ee] = (short8){0,0,0,0,0,0,0,0};
        }
        #pragma unroll
        for (int it = 0; it < 2; ++it) {
            const float* rp = rbf + ge * (INTERM * S_DIM) + (it * 32 + c31) * S_DIM + hh * 8;
            float4v r0 = *(const float4v*)rp;
            float4v r1 = *(const float4v*)(rp + 4);
            rbf_fr[ee][it] = pk8(r0, r1);
        }
    }

    // prefetch m chunk 0
    float4v mc0 = *(const float4v*)(mrow);
    float4v mc1 = *(const float4v*)(mrow + 4);

    f32x4 acc0 = {0.f,0.f,0.f,0.f}, acc1 = {0.f,0.f,0.f,0.f};

    __syncthreads();   // m2t zero visible

    for (int ch = 0; ch < NCH; ++ch) {
        // ---- scatter current m regs into m2t[e][c'][slot] -------------------
        if (valid) {
            #pragma unroll
            for (int jj = 0; jj < 4; ++jj)
                m2t[sbase + jj * KMAXX] = f2bf(mc0[jj]);
            #pragma unroll
            for (int jj = 0; jj < 4; ++jj)
                m2t[sbase + (jj + 4) * KMAXX] = f2bf(mc1[jj]);
        }
        __syncthreads();   // b1: m2t ready

        // ---- MFMA1: sum_k[e](16s x 16c') -> per-edge swk scratch ------------
        #pragma unroll
        for (int ee = 0; ee < 4; ++ee) {
            const int e = w * 4 + ee;
            short8 bf = (q < 2) ? *(const short8*)&m2t[e * EPAD + l15 * KMAXX + q * 8]
                                : (short8){0,0,0,0,0,0,0,0};
            f32x4 d1 = {0.f,0.f,0.f,0.f};
            d1 = __builtin_amdgcn_mfma_f32_16x16x32_bf16(sph_fr[ee], bf, d1, 0, 0, 0);
            // D[row=s=q*4+r][col=c'=l15] -> swk[c'][s]
            *(short4v*)&swk[e * 256 + l15 * 16 + q * 4] = pk4(d1[0], d1[1], d1[2], d1[3]);
        }
        // ---- MFMA2: A_chunk[e](64i x 16c') = rbf[e] @ sum_k[e] -> Ach -------
        #pragma unroll
        for (int ee = 0; ee < 4; ++ee) {
            const int e = w * 4 + ee;
            short8 bfr = (c31 < 16) ? *(const short8*)&swk[e * 256 + c31 * 16 + hh * 8]
                                    : (short8){0,0,0,0,0,0,0,0};
            #pragma unroll
            for (int it = 0; it < 2; ++it) {
                f32x16 d2 = {0.f,0.f,0.f,0.f,0.f,0.f,0.f,0.f,
                             0.f,0.f,0.f,0.f,0.f,0.f,0.f,0.f};
                d2 = __builtin_amdgcn_mfma_f32_32x32x16_bf16(rbf_fr[ee][it], bfr, d2, 0, 0, 0);
                if (c31 < 16) {
                    // D row i = (reg&3) + 8*(reg>>2) + 4*hh (+ it*32), col c' = c31
                    #pragma unroll
                    for (int rg = 0; rg < 4; ++rg) {
                        const int i0 = it * 32 + rg * 8 + hh * 4;
                        *(short4v*)&Ach[c31 * AC_C + e * AC_I + i0] =
                            pk4(d2[rg*4], d2[rg*4+1], d2[rg*4+2], d2[rg*4+3]);
                    }
                }
            }
        }
        __syncthreads();   // b2: Ach ready

        // ---- prefetch next m chunk (HBM latency hides under stage C) --------
        const int chn = (ch + 1) & 7;
        float4v mn0 = *(const float4v*)(mrow + chn * CB);
        float4v mn1 = *(const float4v*)(mrow + chn * CB + 4);

        // ---- stage C: out_tile += X_c(16x64) @ W[c](64x128) -----------------
        #pragma unroll 4
        for (int cc = 0; cc < CB; ++cc) {
            short8 a0 = *(const short8*)&Ach[cc * AC_C + l15 * AC_I + q * 8];
            short8 a1 = *(const short8*)&Ach[cc * AC_C + l15 * AC_I + 32 + q * 8];
            const int c = ch * CB + cc;
            const short* wp0 = wbf + ((long)c * NOUT + (w * 2 + 0) * 16 + l15) * INTERM + q * 8;
            const short* wp1 = wbf + ((long)c * NOUT + (w * 2 + 1) * 16 + l15) * INTERM + q * 8;
            acc0 = __builtin_amdgcn_mfma_f32_16x16x32_bf16(a0, *(const short8*)wp0,        acc0, 0, 0, 0);
            acc0 = __builtin_amdgcn_mfma_f32_16x16x32_bf16(a1, *(const short8*)(wp0 + 32), acc0, 0, 0, 0);
            acc1 = __builtin_amdgcn_mfma_f32_16x16x32_bf16(a0, *(const short8*)wp1,        acc1, 0, 0, 0);
            acc1 = __builtin_amdgcn_mfma_f32_16x16x32_bf16(a1, *(const short8*)(wp1 + 32), acc1, 0, 0, 0);
        }
        __syncthreads();   // b3: Ach/m2t free for next chunk

        mc0 = mn0; mc1 = mn1;
    }

    // ---- epilogue: out[e0 + q*4 + r][w*32 + {0,16} + l15] -------------------
    #pragma unroll
    for (int r = 0; r < 4; ++r) {
        out[(long)(e0 + q * 4 + r) * NOUT + w * 32 + l15]      = acc0[r];
        out[(long)(e0 + q * 4 + r) * NOUT + w * 32 + 16 + l15] = acc1[r];
    }
}

// ---------------------------------------------------------------------------
extern "C" void kernel_launch(void* const* d_in, const int* in_sizes, int n_in,
                              void* d_out, int out_size, void* d_ws, size_t ws_size,
                              hipStream_t stream) {
    const float* rbf = (const float*)d_in[0];
    const float* sph = (const float*)d_in[1];
    const float* m   = (const float*)d_in[2];
    const float* w   = (const float*)d_in[3];
    const int* idr   = (const int*)d_in[4];
    const int* idg   = (const int*)d_in[5];
    float* out       = (float*)d_out;
    short* wbf       = (short*)d_ws;           // 128*128*64 bf16 = 2 MB

    const int E = in_sizes[1] / (S_DIM * KMAXX);   // 50000

    hipLaunchKernelGGL(wtrans_kernel, dim3(EMB), dim3(256), 0, stream, w, wbf);
    hipLaunchKernelGGL(fused_kernel, dim3(E / TE), dim3(256), 0, stream,
                       rbf, sph, m, idr, idg, wbf, out);
}